// Round 1
// baseline (1072.422 us; speedup 1.0000x reference)
//
#include <hip/hip_runtime.h>

typedef _Float16 half_t;
typedef _Float16 half8 __attribute__((ext_vector_type(8)));
typedef float f32x4 __attribute__((ext_vector_type(4)));

// dims
// T=64 B=32 V=32000 E=512 H=512 N=512 DK=256 DV=512, TB=2048

__device__ __forceinline__ void gload_lds16(const void* g, void* l) {
  __builtin_amdgcn_global_load_lds((const __attribute__((address_space(1))) void*)g,
                                   (__attribute__((address_space(3))) void*)l, 16, 0, 0);
}

// ---------------- Wout [512,32000] f32 -> WoutT [32000,512] f16 ----------------
__global__ __launch_bounds__(256) void kConvT(const float* __restrict__ Wout,
                                              half_t* __restrict__ WoutT) {
  __shared__ half_t tile[64][72];
  int n0 = blockIdx.x * 64, k0 = blockIdx.y * 64;
  for (int p = 0; p < 16; p++) {
    int id = p * 256 + threadIdx.x;
    int kk = id >> 6, nn = id & 63;
    tile[nn][kk] = (half_t)Wout[(size_t)(k0 + kk) * 32000 + n0 + nn];
  }
  __syncthreads();
  for (int p = 0; p < 16; p++) {
    int id = p * 256 + threadIdx.x;
    int nn = id >> 6, kk = id & 63;
    WoutT[(size_t)(n0 + nn) * 512 + k0 + kk] = tile[nn][kk];
  }
}

// ---------------- X[row,:] = emb[tok[row],:] ----------------
__global__ __launch_bounds__(256) void kGatherX(const int* __restrict__ tok,
                                                const float* __restrict__ emb,
                                                float* __restrict__ X) {
  int row = blockIdx.x;
  const float* src = emb + (size_t)tok[row] * 512;
  float* dst = X + (size_t)row * 512;
  dst[threadIdx.x] = src[threadIdx.x];
  dst[threadIdx.x + 256] = src[threadIdx.x + 256];
}

// ---------------- Xmean (double) ----------------
__global__ __launch_bounds__(256) void kXmean(const float* __restrict__ X,
                                              double* __restrict__ XM) {
  int t = blockIdx.x;
  for (int e = threadIdx.x; e < 512; e += 256) {
    double s = 0.0;
    for (int b = 0; b < 32; b++) s += (double)X[((size_t)t * 32 + b) * 512 + e];
    XM[(size_t)t * 512 + e] = s * (1.0 / 32.0);
  }
}

// ---------------- Q = X @ Wq (double accum), 4 rows per WG ----------------
__global__ __launch_bounds__(256) void kQ(const float* __restrict__ X,
                                          const float* __restrict__ Wq,
                                          double* __restrict__ Q) {
  __shared__ float xs[4][512];
  int r0 = blockIdx.x * 4;
  for (int p = 0; p < 8; p++) {
    int id = p * 256 + threadIdx.x;
    int r = id >> 9, i = id & 511;
    xs[r][i] = X[(size_t)(r0 + r) * 512 + i];
  }
  __syncthreads();
  int d = threadIdx.x;
  double a0 = 0, a1 = 0, a2 = 0, a3 = 0;
  #pragma unroll 4
  for (int i = 0; i < 512; i++) {
    double w = (double)Wq[(size_t)i * 256 + d];
    a0 += (double)xs[0][i] * w; a1 += (double)xs[1][i] * w;
    a2 += (double)xs[2][i] * w; a3 += (double)xs[3][i] * w;
  }
  Q[(size_t)(r0 + 0) * 256 + d] = a0; Q[(size_t)(r0 + 1) * 256 + d] = a1;
  Q[(size_t)(r0 + 2) * 256 + d] = a2; Q[(size_t)(r0 + 3) * 256 + d] = a3;
}

// ---------------- NK = Xmean @ Wk (double) ----------------
__global__ __launch_bounds__(256) void kNK(const double* __restrict__ XM,
                                           const float* __restrict__ Wk,
                                           double* __restrict__ NK) {
  __shared__ double xm[512];
  int t = blockIdx.x;
  for (int i = threadIdx.x; i < 512; i += 256) xm[i] = XM[(size_t)t * 512 + i];
  __syncthreads();
  int d = threadIdx.x;
  double a = 0;
  #pragma unroll 4
  for (int i = 0; i < 512; i++) a += xm[i] * (double)Wk[(size_t)i * 256 + d];
  NK[(size_t)t * 256 + d] = a;
}

// ---------------- XH = X @ Wh[0:512,:] + bh (fp32), WG=(t,half) ----------------
__global__ __launch_bounds__(256) void kXH(const float* __restrict__ X,
                                           const float* __restrict__ Wh,
                                           const float* __restrict__ bh,
                                           float* __restrict__ XH) {
  __shared__ float xs[16][512];
  int t = blockIdx.x >> 1, hf = blockIdx.x & 1;
  int col = hf * 256 + threadIdx.x;
  float bv = bh[col];
  for (int ph = 0; ph < 2; ph++) {
    __syncthreads();
    for (int p = 0; p < 32; p++) {
      int id = p * 256 + threadIdx.x;
      int b = id >> 9, i = id & 511;
      xs[b][i] = X[((size_t)t * 32 + ph * 16 + b) * 512 + i];
    }
    __syncthreads();
    float acc[16];
    #pragma unroll
    for (int b = 0; b < 16; b++) acc[b] = 0.f;
    #pragma unroll 4
    for (int i = 0; i < 512; i++) {
      float w = Wh[(size_t)i * 512 + col];
      #pragma unroll
      for (int b = 0; b < 16; b++) acc[b] += xs[b][i] * w;
    }
    #pragma unroll
    for (int b = 0; b < 16; b++)
      XH[((size_t)t * 32 + ph * 16 + b) * 512 + col] = acc[b] + bv;
  }
}

// ---------------- scores (fp64) + top-8 + softmax weights ----------------
__global__ __launch_bounds__(512) void kScoreTopk(const double* __restrict__ Qm,
                                                  const double* __restrict__ NKm,
                                                  const float* __restrict__ keys0,
                                                  float* __restrict__ WSo,
                                                  int* __restrict__ ISo) {
  __shared__ double qs[4][256];
  __shared__ double sb[4][512];
  int t = blockIdx.x >> 3, bq = blockIdx.x & 7;
  int r0 = t * 32 + bq * 4;
  for (int id = threadIdx.x; id < 1024; id += 512) {
    int r = id >> 8, d = id & 255;
    qs[r][d] = Qm[(size_t)(r0 + r) * 256 + d];
  }
  __syncthreads();
  {
    int n = threadIdx.x;
    double a0 = 0, a1 = 0, a2 = 0, a3 = 0;
    if (n < t) {
      const double* kp = NKm + (size_t)n * 256;
      #pragma unroll 4
      for (int d = 0; d < 256; d++) {
        double kv = kp[d];
        a0 += qs[0][d] * kv; a1 += qs[1][d] * kv;
        a2 += qs[2][d] * kv; a3 += qs[3][d] * kv;
      }
    } else {
      const float* kp = keys0 + (size_t)n * 256;
      #pragma unroll 4
      for (int d = 0; d < 256; d++) {
        double kv = (double)kp[d];
        a0 += qs[0][d] * kv; a1 += qs[1][d] * kv;
        a2 += qs[2][d] * kv; a3 += qs[3][d] * kv;
      }
    }
    sb[0][n] = a0 * 0.0625; sb[1][n] = a1 * 0.0625;
    sb[2][n] = a2 * 0.0625; sb[3][n] = a3 * 0.0625;
  }
  __syncthreads();
  int wv = threadIdx.x >> 6, lane = threadIdx.x & 63;
  if (wv < 4) {
    double topv[8]; int topi[8];
    for (int it = 0; it < 8; it++) {
      double bvv = -1e300; int bii = 0x7fffffff;
      #pragma unroll
      for (int j = 0; j < 8; j++) {
        int ii = lane + 64 * j;
        double vvv = sb[wv][ii];
        if (vvv > bvv || (vvv == bvv && ii < bii)) { bvv = vvv; bii = ii; }
      }
      #pragma unroll
      for (int s = 32; s > 0; s >>= 1) {
        double ov = __shfl_xor(bvv, s, 64);
        int oi = __shfl_xor(bii, s, 64);
        if (ov > bvv || (ov == bvv && oi < bii)) { bvv = ov; bii = oi; }
      }
      topv[it] = bvv; topi[it] = bii;
      if (lane == 0) sb[wv][bii] = -1e300;
      asm volatile("s_waitcnt lgkmcnt(0)" ::: "memory");
    }
    if (lane == 0) {
      double m = topv[0], ev[8], Z = 0;
      #pragma unroll
      for (int i2 = 0; i2 < 8; i2++) { ev[i2] = exp(topv[i2] - m); Z += ev[i2]; }
      double inv = 1.0 / Z;
      #pragma unroll
      for (int i2 = 0; i2 < 8; i2++) {
        WSo[(size_t)(r0 + wv) * 8 + i2] = (float)(ev[i2] * inv);
        ISo[(size_t)(r0 + wv) * 8 + i2] = topi[i2];
      }
    }
  }
}

// ---------------- per-step dependency flags + zero barrier slots ----------------
__global__ __launch_bounds__(256) void kDeps(const int* __restrict__ ISo,
                                             int* __restrict__ DEP,
                                             int* __restrict__ bars) {
  __shared__ int f;
  int t = blockIdx.x;
  if (threadIdx.x == 0) f = 0;
  __syncthreads();
  int idx = ISo[(size_t)t * 256 + threadIdx.x];
  if (idx < t) atomicOr(&f, 1);
  __syncthreads();
  if (threadIdx.x == 0) DEP[t] = f;
  if (blockIdx.x == 0) bars[threadIdx.x] = 0;
}

// ---------------- fast path: retrieved (values0 only) -> h, hmean ----------------
__global__ __launch_bounds__(256) void kFastH(const float* __restrict__ XHm,
                                              const float* __restrict__ Wh,
                                              const float* __restrict__ vals0,
                                              const float* __restrict__ WSo,
                                              const int* __restrict__ ISo,
                                              half_t* __restrict__ HHm,
                                              float* __restrict__ HMm) {
  __shared__ float rs[16][512];
  __shared__ float wls[32][8];
  __shared__ int   ils[32][8];
  int t = blockIdx.x >> 1, hf = blockIdx.x & 1;
  int col = hf * 256 + threadIdx.x;
  {
    int b = threadIdx.x >> 3, k2 = threadIdx.x & 7;
    wls[b][k2] = WSo[(size_t)(t * 32 + b) * 8 + k2];
    ils[b][k2] = ISo[(size_t)(t * 32 + b) * 8 + k2];
  }
  float hm = 0.f;
  for (int ph = 0; ph < 2; ph++) {
    __syncthreads();
    for (int p = 0; p < 32; p++) {
      int id = p * 256 + threadIdx.x;
      int b = id >> 9, i = id & 511;
      int bg = ph * 16 + b;
      float acc = 0.f;
      #pragma unroll
      for (int k2 = 0; k2 < 8; k2++)
        acc += wls[bg][k2] * vals0[(size_t)ils[bg][k2] * 512 + i];
      rs[b][i] = acc;
    }
    __syncthreads();
    float acc[16];
    #pragma unroll
    for (int b = 0; b < 16; b++) acc[b] = 0.f;
    #pragma unroll 4
    for (int i = 0; i < 512; i++) {
      float w = Wh[(size_t)(512 + i) * 512 + col];
      #pragma unroll
      for (int b = 0; b < 16; b++) acc[b] += rs[b][i] * w;
    }
    #pragma unroll
    for (int b = 0; b < 16; b++) {
      int row = t * 32 + ph * 16 + b;
      float h = tanhf(XHm[(size_t)row * 512 + col] + acc[b]);
      HHm[(size_t)row * 512 + col] = (half_t)h;
      hm += h;
    }
  }
  HMm[(size_t)t * 512 + col] = hm * (1.f / 32.f);
}

// ---------------- NV[t] = hmean[t] @ Wv ----------------
__global__ __launch_bounds__(256) void kNVall(const float* __restrict__ HMm,
                                              const float* __restrict__ Wv,
                                              float* __restrict__ NV) {
  __shared__ float hm[512];
  int t = blockIdx.x;
  hm[threadIdx.x] = HMm[(size_t)t * 512 + threadIdx.x];
  hm[threadIdx.x + 256] = HMm[(size_t)t * 512 + threadIdx.x + 256];
  __syncthreads();
  for (int v = threadIdx.x; v < 512; v += 256) {
    float a = 0.f;
    #pragma unroll 4
    for (int i = 0; i < 512; i++) a += hm[i] * Wv[(size_t)i * 512 + v];
    NV[(size_t)t * 512 + v] = a;
  }
}

// ---------------- grid barrier (64 resident WGs) ----------------
__device__ __forceinline__ void gbar(int* bars, int id, int nwg) {
  __syncthreads();
  if (threadIdx.x == 0) {
    __hip_atomic_fetch_add(&bars[id], 1, __ATOMIC_ACQ_REL, __HIP_MEMORY_SCOPE_AGENT);
    while (__hip_atomic_load(&bars[id], __ATOMIC_ACQUIRE, __HIP_MEMORY_SCOPE_AGENT) < nwg)
      __builtin_amdgcn_s_sleep(4);
  }
  __syncthreads();
}

// ---------------- sequential fixup for steps that selected generated slots ----------------
__global__ __launch_bounds__(256) void kFixup(const int* __restrict__ DEP,
                                              int* __restrict__ bars,
                                              const float* __restrict__ XHm,
                                              const float* __restrict__ Wh,
                                              const float* __restrict__ Wv,
                                              const float* __restrict__ vals0,
                                              const float* __restrict__ WSo,
                                              const int* __restrict__ ISo,
                                              float* __restrict__ NV,
                                              float* __restrict__ RETR,
                                              float* __restrict__ HB,
                                              half_t* __restrict__ HHm) {
  __shared__ float rl[512];
  __shared__ float hm2[512];
  int w = blockIdx.x;
  int barid = 0;
  for (int t = 0; t < 64; t++) {
    if (DEP[t] == 0) continue;
    {  // phase A: retrieved with NV for idx<t
      int b = w >> 1, hf = w & 1;
      int c = hf * 256 + threadIdx.x;
      int row = t * 32 + b;
      float acc = 0.f;
      #pragma unroll
      for (int k2 = 0; k2 < 8; k2++) {
        int idx = ISo[(size_t)row * 8 + k2];
        float wv2 = WSo[(size_t)row * 8 + k2];
        const float* src = (idx < t) ? (NV + (size_t)idx * 512) : (vals0 + (size_t)idx * 512);
        acc += wv2 * src[c];
      }
      RETR[(size_t)b * 512 + c] = acc;
    }
    gbar(bars, barid++, 64);
    if (w < 32) {  // phase B: h row b
      int b = w;
      rl[threadIdx.x] = RETR[(size_t)b * 512 + threadIdx.x];
      rl[threadIdx.x + 256] = RETR[(size_t)b * 512 + threadIdx.x + 256];
      __syncthreads();
      int row = t * 32 + b;
      for (int cc = 0; cc < 2; cc++) {
        int col = cc * 256 + threadIdx.x;
        float acc = 0.f;
        #pragma unroll 4
        for (int i = 0; i < 512; i++) acc += rl[i] * Wh[(size_t)(512 + i) * 512 + col];
        float h = tanhf(XHm[(size_t)row * 512 + col] + acc);
        HB[(size_t)b * 512 + col] = h;
        HHm[(size_t)row * 512 + col] = (half_t)h;
      }
    }
    gbar(bars, barid++, 64);
    if (w == 0) {  // phase C: hmean + NV[t]
      for (int j = threadIdx.x; j < 512; j += 256) {
        float s = 0.f;
        for (int b = 0; b < 32; b++) s += HB[(size_t)b * 512 + j];
        hm2[j] = s * (1.f / 32.f);
      }
      __syncthreads();
      for (int v = threadIdx.x; v < 512; v += 256) {
        float a = 0.f;
        #pragma unroll 4
        for (int i = 0; i < 512; i++) a += hm2[i] * Wv[(size_t)i * 512 + v];
        NV[(size_t)t * 512 + v] = a;
      }
    }
    gbar(bars, barid++, 64);
  }
}

// ---------------- logits = HH @ WoutT^T + bout  (fp16 MFMA, 128x128 tiles) ----------------
__global__ __launch_bounds__(256) void kLogits(const half_t* __restrict__ A,
                                               const half_t* __restrict__ Bm,
                                               const float* __restrict__ bout,
                                               float* __restrict__ C) {
  __shared__ half_t lA[128 * 32];
  __shared__ half_t lB[128 * 32];
  int n0 = blockIdx.x * 128, m0 = blockIdx.y * 128;
  int tid = threadIdx.x, wid = tid >> 6, lane = tid & 63;
  int wm = wid >> 1, wn = wid & 1;
  f32x4 acc[4][4];
  #pragma unroll
  for (int a2 = 0; a2 < 4; a2++)
    #pragma unroll
    for (int b2 = 0; b2 < 4; b2++) acc[a2][b2] = (f32x4){0.f, 0.f, 0.f, 0.f};

  int rA = lane >> 2;          // row within 16-row block
  int cb = (lane & 3) * 8;     // halves offset within row (16B chunks)
  for (int kt = 0; kt < 16; kt++) {
    __syncthreads();
    #pragma unroll
    for (int i2 = 0; i2 < 2; i2++) {
      int blk = wid * 2 + i2;  // 8 blocks of 16 rows
      const half_t* ga = A + ((size_t)(m0 + blk * 16 + rA) * 512 + kt * 32 + cb);
      gload_lds16(ga, (void*)(lA + blk * 512));
      const half_t* gb = Bm + ((size_t)(n0 + blk * 16 + rA) * 512 + kt * 32 + cb);
      gload_lds16(gb, (void*)(lB + blk * 512));
    }
    asm volatile("s_waitcnt vmcnt(0)" ::: "memory");
    __syncthreads();
    half8 af[4], bf[4];
    int koff = (lane >> 4) * 8;
    #pragma unroll
    for (int mf = 0; mf < 4; mf++)
      af[mf] = *(const half8*)&lA[(wm * 64 + mf * 16 + (lane & 15)) * 32 + koff];
    #pragma unroll
    for (int nf = 0; nf < 4; nf++)
      bf[nf] = *(const half8*)&lB[(wn * 64 + nf * 16 + (lane & 15)) * 32 + koff];
    #pragma unroll
    for (int mf = 0; mf < 4; mf++)
      #pragma unroll
      for (int nf = 0; nf < 4; nf++)
        acc[mf][nf] = __builtin_amdgcn_mfma_f32_16x16x32_f16(af[mf], bf[nf], acc[mf][nf], 0, 0, 0);
  }
  #pragma unroll
  for (int nf = 0; nf < 4; nf++) {
    int col = n0 + wn * 64 + nf * 16 + (lane & 15);
    float bv = bout[col];
    #pragma unroll
    for (int mf = 0; mf < 4; mf++) {
      int rbase = m0 + wm * 64 + mf * 16 + (lane >> 4) * 4;
      #pragma unroll
      for (int r = 0; r < 4; r++)
        C[(size_t)(rbase + r) * 32000 + col] = acc[mf][nf][r] + bv;
    }
  }
}

extern "C" void kernel_launch(void* const* d_in, const int* in_sizes, int n_in,
                              void* d_out, int out_size, void* d_ws, size_t ws_size,
                              hipStream_t stream) {
  (void)in_sizes; (void)n_in; (void)out_size; (void)ws_size;
  const int*   tok   = (const int*)d_in[0];
  const float* emb   = (const float*)d_in[1];
  const float* Wq    = (const float*)d_in[2];
  const float* Wk    = (const float*)d_in[3];
  const float* Wv    = (const float*)d_in[4];
  const float* Wh    = (const float*)d_in[5];
  const float* bh    = (const float*)d_in[6];
  const float* Wout  = (const float*)d_in[7];
  const float* bout  = (const float*)d_in[8];
  const float* keys0 = (const float*)d_in[9];
  const float* vals0 = (const float*)d_in[10];
  float* Cout = (float*)d_out;

  char* ws = (char*)d_ws;
  size_t off = 0;
  auto alloc = [&](size_t bytes) -> char* {
    char* p = ws + off;
    off += (bytes + 255) & ~(size_t)255;
    return p;
  };
  half_t* WoutT = (half_t*)alloc(32768000);  // [32000][512] f16
  float*  X     = (float*) alloc(4194304);   // [2048][512]
  double* Qd    = (double*)alloc(4194304);   // [2048][256]
  double* NKd   = (double*)alloc(131072);    // [64][256]
  double* XM    = (double*)alloc(262144);    // [64][512]
  float*  XH    = (float*) alloc(4194304);   // [2048][512]
  float*  WSb   = (float*) alloc(65536);     // [2048][8]
  int*    ISb   = (int*)   alloc(65536);     // [2048][8]
  float*  NV    = (float*) alloc(131072);    // [64][512]
  half_t* HH    = (half_t*)alloc(2097152);   // [2048][512]
  float*  HM    = (float*) alloc(131072);    // [64][512]
  float*  RETR  = (float*) alloc(65536);     // [32][512]
  float*  HB    = (float*) alloc(65536);     // [32][512]
  int*    DEP   = (int*)   alloc(256);       // [64]
  int*    bars  = (int*)   alloc(1024);      // [256]

  kConvT<<<dim3(500, 8), 256, 0, stream>>>(Wout, WoutT);
  kGatherX<<<2048, 256, 0, stream>>>(tok, emb, X);
  kXmean<<<64, 256, 0, stream>>>(X, XM);
  kQ<<<512, 256, 0, stream>>>(X, Wq, Qd);
  kNK<<<64, 256, 0, stream>>>(XM, Wk, NKd);
  kXH<<<128, 256, 0, stream>>>(X, Wh, bh, XH);
  kScoreTopk<<<512, 512, 0, stream>>>(Qd, NKd, keys0, WSb, ISb);
  kDeps<<<64, 256, 0, stream>>>(ISb, DEP, bars);
  kFastH<<<128, 256, 0, stream>>>(XH, Wh, vals0, WSb, ISb, HH, HM);
  kNVall<<<64, 256, 0, stream>>>(HM, Wv, NV);
  kFixup<<<64, 256, 0, stream>>>(DEP, bars, XH, Wh, Wv, vals0, WSb, ISb, NV, RETR, HB, HH);
  kLogits<<<dim3(250, 16), 256, 0, stream>>>(HH, WoutT, bout, Cout);
}

// Round 3
// 533.151 us; speedup vs baseline: 2.0115x; 2.0115x over previous
//
#include <hip/hip_runtime.h>

typedef _Float16 half_t;
typedef _Float16 half8 __attribute__((ext_vector_type(8)));
typedef float f32x4 __attribute__((ext_vector_type(4)));

// dims: T=64 B=32 V=32000 E=512 H=512 N=512 DK=256 DV=512, TB=2048

__device__ __forceinline__ void gload_lds16(const void* g, void* l) {
  __builtin_amdgcn_global_load_lds((const __attribute__((address_space(1))) void*)g,
                                   (__attribute__((address_space(3))) void*)l, 16, 0, 0);
}

// ---------------- Wout [512,32000] f32 -> WoutT [32000,512] f16 ----------------
__global__ __launch_bounds__(256) void kConvT(const float* __restrict__ Wout,
                                              half_t* __restrict__ WoutT) {
  __shared__ half_t tile[64][66];
  int n0 = blockIdx.x * 64, k0 = blockIdx.y * 64;
  for (int p = 0; p < 16; p++) {
    int id = p * 256 + threadIdx.x;
    int kk = id >> 6, nn = id & 63;
    tile[nn][kk] = (half_t)Wout[(size_t)(k0 + kk) * 32000 + n0 + nn];
  }
  __syncthreads();
  for (int p = 0; p < 16; p++) {
    int id = p * 256 + threadIdx.x;
    int nn = id >> 6, kk = id & 63;
    WoutT[(size_t)(n0 + nn) * 512 + k0 + kk] = tile[nn][kk];
  }
}

// ---------------- Wh [1024,512] f32 -> W1T/W2T [512][512] f16 (transposed) ------
__global__ __launch_bounds__(256) void kWhT(const float* __restrict__ Wh,
                                            half_t* __restrict__ W1T,
                                            half_t* __restrict__ W2T) {
  __shared__ half_t tile[64][66];
  int n0 = blockIdx.x * 64, k0 = blockIdx.y * 64;
  for (int p = 0; p < 16; p++) {
    int id = p * 256 + threadIdx.x;
    int kk = id >> 6, nn = id & 63;
    tile[nn][kk] = (half_t)Wh[(size_t)(k0 + kk) * 512 + n0 + nn];
  }
  __syncthreads();
  half_t* out = (k0 < 512) ? W1T : W2T;
  int kb = k0 & 511;
  for (int p = 0; p < 16; p++) {
    int id = p * 256 + threadIdx.x;
    int nn = id >> 6, kk = id & 63;
    out[(size_t)(n0 + nn) * 512 + kb + kk] = tile[nn][kk];
  }
}

// ---------------- X[row,:] = emb[tok[row],:] (f32 + f16 copies) ----------------
__global__ __launch_bounds__(256) void kGatherX(const int* __restrict__ tok,
                                                const float* __restrict__ emb,
                                                float* __restrict__ X,
                                                half_t* __restrict__ Xh) {
  int row = blockIdx.x;
  const float* src = emb + (size_t)tok[row] * 512;
  float* dst = X + (size_t)row * 512;
  half_t* dsth = Xh + (size_t)row * 512;
  float v0 = src[threadIdx.x], v1 = src[threadIdx.x + 256];
  dst[threadIdx.x] = v0; dst[threadIdx.x + 256] = v1;
  dsth[threadIdx.x] = (half_t)v0; dsth[threadIdx.x + 256] = (half_t)v1;
}

// ---------------- Xmean (double) ----------------
__global__ __launch_bounds__(256) void kXmean(const float* __restrict__ X,
                                              double* __restrict__ XM) {
  int t = blockIdx.x;
  for (int e = threadIdx.x; e < 512; e += 256) {
    double s = 0.0;
    for (int b = 0; b < 32; b++) s += (double)X[((size_t)t * 32 + b) * 512 + e];
    XM[(size_t)t * 512 + e] = s * (1.0 / 32.0);
  }
}

// ---------------- Q = X @ Wq (double accum), 4 rows per WG ----------------
__global__ __launch_bounds__(256) void kQ(const float* __restrict__ X,
                                          const float* __restrict__ Wq,
                                          double* __restrict__ Q) {
  __shared__ float xs[4][512];
  int r0 = blockIdx.x * 4;
  for (int p = 0; p < 8; p++) {
    int id = p * 256 + threadIdx.x;
    int r = id >> 9, i = id & 511;
    xs[r][i] = X[(size_t)(r0 + r) * 512 + i];
  }
  __syncthreads();
  int d = threadIdx.x;
  double a0 = 0, a1 = 0, a2 = 0, a3 = 0;
  #pragma unroll 4
  for (int i = 0; i < 512; i++) {
    double w = (double)Wq[(size_t)i * 256 + d];
    a0 += (double)xs[0][i] * w; a1 += (double)xs[1][i] * w;
    a2 += (double)xs[2][i] * w; a3 += (double)xs[3][i] * w;
  }
  Q[(size_t)(r0 + 0) * 256 + d] = a0; Q[(size_t)(r0 + 1) * 256 + d] = a1;
  Q[(size_t)(r0 + 2) * 256 + d] = a2; Q[(size_t)(r0 + 3) * 256 + d] = a3;
}

// ---------------- NK = Xmean @ Wk (double) ----------------
__global__ __launch_bounds__(256) void kNK(const double* __restrict__ XM,
                                           const float* __restrict__ Wk,
                                           double* __restrict__ NK) {
  __shared__ double xm[512];
  int t = blockIdx.x;
  for (int i = threadIdx.x; i < 512; i += 256) xm[i] = XM[(size_t)t * 512 + i];
  __syncthreads();
  int d = threadIdx.x;
  double a = 0;
  #pragma unroll 4
  for (int i = 0; i < 512; i++) a += xm[i] * (double)Wk[(size_t)i * 256 + d];
  NK[(size_t)t * 256 + d] = a;
}

// ---------------- scores (fp64) + top-8 + softmax weights ----------------
__global__ __launch_bounds__(512) void kScoreTopk(const double* __restrict__ Qm,
                                                  const double* __restrict__ NKm,
                                                  const float* __restrict__ keys0,
                                                  float* __restrict__ WSo,
                                                  int* __restrict__ ISo) {
  __shared__ double qs[4][256];
  __shared__ double sb[4][512];
  int t = blockIdx.x >> 3, bq = blockIdx.x & 7;
  int r0 = t * 32 + bq * 4;
  for (int id = threadIdx.x; id < 1024; id += 512) {
    int r = id >> 8, d = id & 255;
    qs[r][d] = Qm[(size_t)(r0 + r) * 256 + d];
  }
  __syncthreads();
  {
    int n = threadIdx.x;
    double a0 = 0, a1 = 0, a2 = 0, a3 = 0;
    if (n < t) {
      const double* kp = NKm + (size_t)n * 256;
      #pragma unroll 4
      for (int d = 0; d < 256; d++) {
        double kv = kp[d];
        a0 += qs[0][d] * kv; a1 += qs[1][d] * kv;
        a2 += qs[2][d] * kv; a3 += qs[3][d] * kv;
      }
    } else {
      const float* kp = keys0 + (size_t)n * 256;
      #pragma unroll 4
      for (int d = 0; d < 256; d++) {
        double kv = (double)kp[d];
        a0 += qs[0][d] * kv; a1 += qs[1][d] * kv;
        a2 += qs[2][d] * kv; a3 += qs[3][d] * kv;
      }
    }
    sb[0][n] = a0 * 0.0625; sb[1][n] = a1 * 0.0625;
    sb[2][n] = a2 * 0.0625; sb[3][n] = a3 * 0.0625;
  }
  __syncthreads();
  int wv = threadIdx.x >> 6, lane = threadIdx.x & 63;
  if (wv < 4) {
    double topv[8]; int topi[8];
    for (int it = 0; it < 8; it++) {
      double bvv = -1e300; int bii = 0x7fffffff;
      #pragma unroll
      for (int j = 0; j < 8; j++) {
        int ii = lane + 64 * j;
        double vvv = sb[wv][ii];
        if (vvv > bvv || (vvv == bvv && ii < bii)) { bvv = vvv; bii = ii; }
      }
      #pragma unroll
      for (int s = 32; s > 0; s >>= 1) {
        double ov = __shfl_xor(bvv, s, 64);
        int oi = __shfl_xor(bii, s, 64);
        if (ov > bvv || (ov == bvv && oi < bii)) { bvv = ov; bii = oi; }
      }
      topv[it] = bvv; topi[it] = bii;
      if (lane == 0) sb[wv][bii] = -1e300;
      asm volatile("s_waitcnt lgkmcnt(0)" ::: "memory");
    }
    if (lane == 0) {
      double m = topv[0], ev[8], Z = 0;
      #pragma unroll
      for (int i2 = 0; i2 < 8; i2++) { ev[i2] = exp(topv[i2] - m); Z += ev[i2]; }
      double inv = 1.0 / Z;
      #pragma unroll
      for (int i2 = 0; i2 < 8; i2++) {
        WSo[(size_t)(r0 + wv) * 8 + i2] = (float)(ev[i2] * inv);
        ISo[(size_t)(r0 + wv) * 8 + i2] = topi[i2];
      }
    }
  }
}

// ---------------- per-step dependency flags + zero barrier slots ----------------
__global__ __launch_bounds__(256) void kDeps(const int* __restrict__ ISo,
                                             int* __restrict__ DEP,
                                             int* __restrict__ bars) {
  __shared__ int f;
  int t = blockIdx.x;
  if (threadIdx.x == 0) f = 0;
  __syncthreads();
  int idx = ISo[(size_t)t * 256 + threadIdx.x];
  if (idx < t) atomicOr(&f, 1);
  __syncthreads();
  if (threadIdx.x == 0) DEP[t] = f;
  if (blockIdx.x == 0) bars[threadIdx.x] = 0;
}

// ---------------- fast-path retrieved -> fp16 [2048][512] ----------------
__global__ __launch_bounds__(256) void kRetr(const float* __restrict__ vals0,
                                             const float* __restrict__ WSo,
                                             const int* __restrict__ ISo,
                                             half_t* __restrict__ R16) {
  __shared__ float wl[8];
  __shared__ int il[8];
  int row = blockIdx.x;
  if (threadIdx.x < 8) {
    wl[threadIdx.x] = WSo[(size_t)row * 8 + threadIdx.x];
    il[threadIdx.x] = ISo[(size_t)row * 8 + threadIdx.x];
  }
  __syncthreads();
  int c = threadIdx.x;
  float a0 = 0.f, a1 = 0.f;
  #pragma unroll
  for (int k2 = 0; k2 < 8; k2++) {
    const float* src = vals0 + (size_t)il[k2] * 512;
    a0 += wl[k2] * src[c];
    a1 += wl[k2] * src[c + 256];
  }
  R16[(size_t)row * 512 + c] = (half_t)a0;
  R16[(size_t)row * 512 + c + 256] = (half_t)a1;
}

// ---------------- XH = Xh @ W1T^T + bh (fp16 MFMA -> fp32) ----------------
__global__ __launch_bounds__(256) void kXHmfma(const half_t* __restrict__ A,
                                               const half_t* __restrict__ Bm,
                                               const float* __restrict__ bh,
                                               float* __restrict__ XH) {
  __shared__ half_t lA[128 * 32];
  __shared__ half_t lB[128 * 32];
  int n0 = blockIdx.x * 128, m0 = blockIdx.y * 128;
  int tid = threadIdx.x, wid = tid >> 6, lane = tid & 63;
  int wm = wid >> 1, wn = wid & 1;
  f32x4 acc[4][4];
  #pragma unroll
  for (int a2 = 0; a2 < 4; a2++)
    #pragma unroll
    for (int b2 = 0; b2 < 4; b2++) acc[a2][b2] = (f32x4){0.f, 0.f, 0.f, 0.f};
  int rA = lane >> 2, cb = (lane & 3) * 8;
  for (int kt = 0; kt < 16; kt++) {
    __syncthreads();
    #pragma unroll
    for (int i2 = 0; i2 < 2; i2++) {
      int blk = wid * 2 + i2;
      gload_lds16(A + ((size_t)(m0 + blk * 16 + rA) * 512 + kt * 32 + cb), (void*)(lA + blk * 512));
      gload_lds16(Bm + ((size_t)(n0 + blk * 16 + rA) * 512 + kt * 32 + cb), (void*)(lB + blk * 512));
    }
    asm volatile("s_waitcnt vmcnt(0)" ::: "memory");
    __syncthreads();
    half8 af[4], bf[4];
    int koff = (lane >> 4) * 8;
    #pragma unroll
    for (int mf = 0; mf < 4; mf++)
      af[mf] = *(const half8*)&lA[(wm * 64 + mf * 16 + (lane & 15)) * 32 + koff];
    #pragma unroll
    for (int nf = 0; nf < 4; nf++)
      bf[nf] = *(const half8*)&lB[(wn * 64 + nf * 16 + (lane & 15)) * 32 + koff];
    #pragma unroll
    for (int mf = 0; mf < 4; mf++)
      #pragma unroll
      for (int nf = 0; nf < 4; nf++)
        acc[mf][nf] = __builtin_amdgcn_mfma_f32_16x16x32_f16(af[mf], bf[nf], acc[mf][nf], 0, 0, 0);
  }
  #pragma unroll
  for (int nf = 0; nf < 4; nf++) {
    int col = n0 + wn * 64 + nf * 16 + (lane & 15);
    float bv = bh[col];
    #pragma unroll
    for (int mf = 0; mf < 4; mf++) {
      int rbase = m0 + wm * 64 + mf * 16 + (lane >> 4) * 4;
      #pragma unroll
      for (int r = 0; r < 4; r++)
        XH[(size_t)(rbase + r) * 512 + col] = acc[mf][nf][r] + bv;
    }
  }
}

// ---------------- HH = tanh(XH + R16 @ W2T^T) fp16; HM = per-t mean ----------------
__global__ __launch_bounds__(256) void kH(const half_t* __restrict__ A,
                                          const half_t* __restrict__ Bm,
                                          const float* __restrict__ XH,
                                          half_t* __restrict__ HH,
                                          float* __restrict__ HM) {
  __shared__ half_t lA[128 * 32];
  __shared__ half_t lB[128 * 32];
  int n0 = blockIdx.x * 128, m0 = blockIdx.y * 128;
  int tid = threadIdx.x, wid = tid >> 6, lane = tid & 63;
  int wm = wid >> 1, wn = wid & 1;
  f32x4 acc[4][4];
  #pragma unroll
  for (int a2 = 0; a2 < 4; a2++)
    #pragma unroll
    for (int b2 = 0; b2 < 4; b2++) acc[a2][b2] = (f32x4){0.f, 0.f, 0.f, 0.f};
  int rA = lane >> 2, cb = (lane & 3) * 8;
  for (int kt = 0; kt < 16; kt++) {
    __syncthreads();
    #pragma unroll
    for (int i2 = 0; i2 < 2; i2++) {
      int blk = wid * 2 + i2;
      gload_lds16(A + ((size_t)(m0 + blk * 16 + rA) * 512 + kt * 32 + cb), (void*)(lA + blk * 512));
      gload_lds16(Bm + ((size_t)(n0 + blk * 16 + rA) * 512 + kt * 32 + cb), (void*)(lB + blk * 512));
    }
    asm volatile("s_waitcnt vmcnt(0)" ::: "memory");
    __syncthreads();
    half8 af[4], bf[4];
    int koff = (lane >> 4) * 8;
    #pragma unroll
    for (int mf = 0; mf < 4; mf++)
      af[mf] = *(const half8*)&lA[(wm * 64 + mf * 16 + (lane & 15)) * 32 + koff];
    #pragma unroll
    for (int nf = 0; nf < 4; nf++)
      bf[nf] = *(const half8*)&lB[(wn * 64 + nf * 16 + (lane & 15)) * 32 + koff];
    #pragma unroll
    for (int mf = 0; mf < 4; mf++)
      #pragma unroll
      for (int nf = 0; nf < 4; nf++)
        acc[mf][nf] = __builtin_amdgcn_mfma_f32_16x16x32_f16(af[mf], bf[nf], acc[mf][nf], 0, 0, 0);
  }
  // epilogue: tanh + HH write + per-t column means (t spans exactly 32 rows = 2 mf blocks)
  #pragma unroll
  for (int tt = 0; tt < 2; tt++) {
    #pragma unroll
    for (int nf = 0; nf < 4; nf++) {
      int col = n0 + wn * 64 + nf * 16 + (lane & 15);
      float cs = 0.f;
      #pragma unroll
      for (int mfp = 0; mfp < 2; mfp++) {
        int mf = tt * 2 + mfp;
        int rbase = m0 + wm * 64 + mf * 16 + (lane >> 4) * 4;
        #pragma unroll
        for (int r = 0; r < 4; r++) {
          float v = tanhf(XH[(size_t)(rbase + r) * 512 + col] + acc[mf][nf][r]);
          HH[(size_t)(rbase + r) * 512 + col] = (half_t)v;
          cs += v;
        }
      }
      cs += __shfl_xor(cs, 16, 64);
      cs += __shfl_xor(cs, 32, 64);
      if ((lane >> 4) == 0) {
        int t = (m0 >> 5) + wm * 2 + tt;
        HM[(size_t)t * 512 + col] = cs * (1.f / 32.f);
      }
    }
  }
}

// ---------------- NV[t] = hmean[t] @ Wv ----------------
__global__ __launch_bounds__(256) void kNVall(const float* __restrict__ HMm,
                                              const float* __restrict__ Wv,
                                              float* __restrict__ NV) {
  __shared__ float hm[512];
  int t = blockIdx.x;
  hm[threadIdx.x] = HMm[(size_t)t * 512 + threadIdx.x];
  hm[threadIdx.x + 256] = HMm[(size_t)t * 512 + threadIdx.x + 256];
  __syncthreads();
  for (int v = threadIdx.x; v < 512; v += 256) {
    float a = 0.f;
    #pragma unroll 4
    for (int i = 0; i < 512; i++) a += hm[i] * Wv[(size_t)i * 512 + v];
    NV[(size_t)t * 512 + v] = a;
  }
}

// ---------------- grid barrier (64 resident WGs) ----------------
__device__ __forceinline__ void gbar(int* bars, int id, int nwg) {
  __syncthreads();
  if (threadIdx.x == 0) {
    __hip_atomic_fetch_add(&bars[id], 1, __ATOMIC_ACQ_REL, __HIP_MEMORY_SCOPE_AGENT);
    while (__hip_atomic_load(&bars[id], __ATOMIC_ACQUIRE, __HIP_MEMORY_SCOPE_AGENT) < nwg)
      __builtin_amdgcn_s_sleep(4);
  }
  __syncthreads();
}

// ---------------- sequential fixup for steps that selected generated slots ----------------
__global__ __launch_bounds__(256) void kFixup(const int* __restrict__ DEP,
                                              int* __restrict__ bars,
                                              const float* __restrict__ XHm,
                                              const float* __restrict__ Wh,
                                              const float* __restrict__ Wv,
                                              const float* __restrict__ vals0,
                                              const float* __restrict__ WSo,
                                              const int* __restrict__ ISo,
                                              float* __restrict__ NV,
                                              float* __restrict__ RETR,
                                              float* __restrict__ HB,
                                              half_t* __restrict__ HHm) {
  __shared__ float rl[512];
  __shared__ float hm2[512];
  int w = blockIdx.x;
  int barid = 0;
  for (int t = 0; t < 64; t++) {
    if (DEP[t] == 0) continue;
    {  // phase A: retrieved with NV for idx<t
      int b = w >> 1, hf = w & 1;
      int c = hf * 256 + threadIdx.x;
      int row = t * 32 + b;
      float acc = 0.f;
      #pragma unroll
      for (int k2 = 0; k2 < 8; k2++) {
        int idx = ISo[(size_t)row * 8 + k2];
        float wv2 = WSo[(size_t)row * 8 + k2];
        const float* src = (idx < t) ? (NV + (size_t)idx * 512) : (vals0 + (size_t)idx * 512);
        acc += wv2 * src[c];
      }
      RETR[(size_t)b * 512 + c] = acc;
    }
    gbar(bars, barid++, 64);
    if (w < 32) {  // phase B: h row b
      int b = w;
      rl[threadIdx.x] = RETR[(size_t)b * 512 + threadIdx.x];
      rl[threadIdx.x + 256] = RETR[(size_t)b * 512 + threadIdx.x + 256];
      __syncthreads();
      int row = t * 32 + b;
      for (int cc = 0; cc < 2; cc++) {
        int col = cc * 256 + threadIdx.x;
        float acc = 0.f;
        #pragma unroll 4
        for (int i = 0; i < 512; i++) acc += rl[i] * Wh[(size_t)(512 + i) * 512 + col];
        float h = tanhf(XHm[(size_t)row * 512 + col] + acc);
        HB[(size_t)b * 512 + col] = h;
        HHm[(size_t)row * 512 + col] = (half_t)h;
      }
    }
    gbar(bars, barid++, 64);
    if (w == 0) {  // phase C: hmean + NV[t]
      for (int j = threadIdx.x; j < 512; j += 256) {
        float s = 0.f;
        for (int b = 0; b < 32; b++) s += HB[(size_t)b * 512 + j];
        hm2[j] = s * (1.f / 32.f);
      }
      __syncthreads();
      for (int v = threadIdx.x; v < 512; v += 256) {
        float a = 0.f;
        #pragma unroll 4
        for (int i = 0; i < 512; i++) a += hm2[i] * Wv[(size_t)i * 512 + v];
        NV[(size_t)t * 512 + v] = a;
      }
    }
    gbar(bars, barid++, 64);
  }
}

// ---------------- logits = HH @ WoutT^T + bout  (fp16 MFMA, 128x128 tiles) ----------------
__global__ __launch_bounds__(256) void kLogits(const half_t* __restrict__ A,
                                               const half_t* __restrict__ Bm,
                                               const float* __restrict__ bout,
                                               float* __restrict__ C) {
  __shared__ half_t lA[128 * 32];
  __shared__ half_t lB[128 * 32];
  int n0 = blockIdx.x * 128, m0 = blockIdx.y * 128;
  int tid = threadIdx.x, wid = tid >> 6, lane = tid & 63;
  int wm = wid >> 1, wn = wid & 1;
  f32x4 acc[4][4];
  #pragma unroll
  for (int a2 = 0; a2 < 4; a2++)
    #pragma unroll
    for (int b2 = 0; b2 < 4; b2++) acc[a2][b2] = (f32x4){0.f, 0.f, 0.f, 0.f};

  int rA = lane >> 2;
  int cb = (lane & 3) * 8;
  for (int kt = 0; kt < 16; kt++) {
    __syncthreads();
    #pragma unroll
    for (int i2 = 0; i2 < 2; i2++) {
      int blk = wid * 2 + i2;
      gload_lds16(A + ((size_t)(m0 + blk * 16 + rA) * 512 + kt * 32 + cb), (void*)(lA + blk * 512));
      gload_lds16(Bm + ((size_t)(n0 + blk * 16 + rA) * 512 + kt * 32 + cb), (void*)(lB + blk * 512));
    }
    asm volatile("s_waitcnt vmcnt(0)" ::: "memory");
    __syncthreads();
    half8 af[4], bf[4];
    int koff = (lane >> 4) * 8;
    #pragma unroll
    for (int mf = 0; mf < 4; mf++)
      af[mf] = *(const half8*)&lA[(wm * 64 + mf * 16 + (lane & 15)) * 32 + koff];
    #pragma unroll
    for (int nf = 0; nf < 4; nf++)
      bf[nf] = *(const half8*)&lB[(wn * 64 + nf * 16 + (lane & 15)) * 32 + koff];
    #pragma unroll
    for (int mf = 0; mf < 4; mf++)
      #pragma unroll
      for (int nf = 0; nf < 4; nf++)
        acc[mf][nf] = __builtin_amdgcn_mfma_f32_16x16x32_f16(af[mf], bf[nf], acc[mf][nf], 0, 0, 0);
  }
  #pragma unroll
  for (int nf = 0; nf < 4; nf++) {
    int col = n0 + wn * 64 + nf * 16 + (lane & 15);
    float bv = bout[col];
    #pragma unroll
    for (int mf = 0; mf < 4; mf++) {
      int rbase = m0 + wm * 64 + mf * 16 + (lane >> 4) * 4;
      #pragma unroll
      for (int r = 0; r < 4; r++)
        C[(size_t)(rbase + r) * 32000 + col] = acc[mf][nf][r] + bv;
    }
  }
}

extern "C" void kernel_launch(void* const* d_in, const int* in_sizes, int n_in,
                              void* d_out, int out_size, void* d_ws, size_t ws_size,
                              hipStream_t stream) {
  (void)in_sizes; (void)n_in; (void)out_size; (void)ws_size;
  const int*   tok   = (const int*)d_in[0];
  const float* emb   = (const float*)d_in[1];
  const float* Wq    = (const float*)d_in[2];
  const float* Wk    = (const float*)d_in[3];
  const float* Wv    = (const float*)d_in[4];
  const float* Wh    = (const float*)d_in[5];
  const float* bh    = (const float*)d_in[6];
  const float* Wout  = (const float*)d_in[7];
  const float* bout  = (const float*)d_in[8];
  const float* keys0 = (const float*)d_in[9];
  const float* vals0 = (const float*)d_in[10];
  float* Cout = (float*)d_out;

  char* ws = (char*)d_ws;
  size_t off = 0;
  auto alloc = [&](size_t bytes) -> char* {
    char* p = ws + off;
    off += (bytes + 255) & ~(size_t)255;
    return p;
  };
  half_t* WoutT = (half_t*)alloc(32768000);  // [32000][512] f16
  half_t* W1T   = (half_t*)alloc(524288);    // [512][512] f16
  half_t* W2T   = (half_t*)alloc(524288);    // [512][512] f16
  float*  X     = (float*) alloc(4194304);   // [2048][512]
  half_t* Xh    = (half_t*)alloc(2097152);   // [2048][512] f16
  double* Qd    = (double*)alloc(4194304);   // [2048][256]
  double* NKd   = (double*)alloc(131072);    // [64][256]
  double* XM    = (double*)alloc(262144);    // [64][512]
  float*  XH    = (float*) alloc(4194304);   // [2048][512]
  float*  WSb   = (float*) alloc(65536);     // [2048][8]
  int*    ISb   = (int*)   alloc(65536);     // [2048][8]
  float*  NV    = (float*) alloc(131072);    // [64][512]
  half_t* R16   = (half_t*)alloc(2097152);   // [2048][512] f16
  half_t* HH    = (half_t*)alloc(2097152);   // [2048][512]
  float*  HM    = (float*) alloc(131072);    // [64][512]
  float*  RETR  = (float*) alloc(65536);     // [32][512]
  float*  HB    = (float*) alloc(65536);     // [32][512]
  int*    DEP   = (int*)   alloc(256);       // [64]
  int*    bars  = (int*)   alloc(1024);      // [256]

  kConvT<<<dim3(500, 8), 256, 0, stream>>>(Wout, WoutT);
  kWhT<<<dim3(8, 16), 256, 0, stream>>>(Wh, W1T, W2T);
  kGatherX<<<2048, 256, 0, stream>>>(tok, emb, X, Xh);
  kXmean<<<64, 256, 0, stream>>>(X, XM);
  kQ<<<512, 256, 0, stream>>>(X, Wq, Qd);
  kNK<<<64, 256, 0, stream>>>(XM, Wk, NKd);
  kScoreTopk<<<512, 512, 0, stream>>>(Qd, NKd, keys0, WSb, ISb);
  kDeps<<<64, 256, 0, stream>>>(ISb, DEP, bars);
  kRetr<<<2048, 256, 0, stream>>>(vals0, WSb, ISb, R16);
  kXHmfma<<<dim3(4, 16), 256, 0, stream>>>(Xh, W1T, bh, XH);
  kH<<<dim3(4, 16), 256, 0, stream>>>(R16, W2T, XH, HH, HM);
  kNVall<<<64, 256, 0, stream>>>(HM, Wv, NV);
  kFixup<<<64, 256, 0, stream>>>(DEP, bars, XH, Wh, Wv, vals0, WSb, ISb, NV, RETR, HB, HH);
  kLogits<<<dim3(250, 16), 256, 0, stream>>>(HH, WoutT, bout, Cout);
}